// Round 6
// baseline (295.490 us; speedup 1.0000x reference)
//
#include <hip/hip_runtime.h>
#include <hip/hip_bf16.h>
#include <math.h>

#define NSENT 65536
#define NBAGS 4096
#define DIM 768
#define D4 192            // DIM/4
#define FLATC 53
#define CPAD 64           // padded class count for probs MFMA
#define KTOT 2304         // 3*DIM
#define K4 576            // KTOT/4

typedef short bf16x8 __attribute__((ext_vector_type(8)));
typedef float f32x4 __attribute__((ext_vector_type(4)));

__device__ __forceinline__ float wsum(float v) {
#pragma unroll
  for (int o = 32; o; o >>= 1) v += __shfl_xor(v, o);
  return v;
}
__device__ __forceinline__ float wmax(float v) {
#pragma unroll
  for (int o = 32; o; o >>= 1) v = fmaxf(v, __shfl_xor(v, o));
  return v;
}
__device__ __forceinline__ float dot4(float4 a, float4 b) {
  return a.x * b.x + a.y * b.y + a.z * b.z + a.w * b.w;
}
__device__ __forceinline__ unsigned short f2bf(float f) {
  union { __hip_bfloat16 b; unsigned short s; } cv;
  cv.b = __float2bfloat16(f);
  return cv.s;
}

// ---- K1: relation_weight f32[53][2304] -> bf16 padded [64][2304] ----
__global__ __launch_bounds__(256) void rwcvt(const float* __restrict__ rw,
                                             unsigned short* __restrict__ rw16) {
  const int idx = blockIdx.x * 256 + threadIdx.x;
  if (idx < CPAD * KTOT) {
    const int row = idx / KTOT;
    rw16[idx] = f2bf(row < FLATC ? rw[idx] : 0.f);
  }
}

// ---- K2: logits for ALL sentences, wave = 2 sentences (R4 known-good) ----
__global__ __launch_bounds__(256) void logit_kernel(
    const float* __restrict__ x, const int* __restrict__ q,
    const float* __restrict__ aw, float* __restrict__ lgout) {
  const int wid = (blockIdx.x * 256 + threadIdx.x) >> 6;
  const int lane = threadIdx.x & 63;
  const int n0 = wid * 2;
  if (n0 >= NSENT) return;
  const int n1 = n0 + 1;

  const int qa0 = q[3 * n0 + 0], qa1 = q[3 * n0 + 1], qa2 = q[3 * n0 + 2];
  const int qb0 = q[3 * n1 + 0], qb1 = q[3 * n1 + 1], qb2 = q[3 * n1 + 2];

  const float4* __restrict__ X4 = (const float4*)x;
  const float4* __restrict__ AW4 = (const float4*)aw;
  const float4* xr0 = X4 + (size_t)n0 * D4;
  const float4* xr1 = X4 + (size_t)n1 * D4;
  const float4* A00 = AW4 + (size_t)qa0 * D4;
  const float4* A01 = AW4 + (size_t)qa1 * D4;
  const float4* A02 = AW4 + (size_t)qa2 * D4;
  const float4* A10 = AW4 + (size_t)qb0 * D4;
  const float4* A11 = AW4 + (size_t)qb1 * D4;
  const float4* A12 = AW4 + (size_t)qb2 * D4;

  float p00 = 0.f, p01 = 0.f, p02 = 0.f;
  float p10 = 0.f, p11 = 0.f, p12 = 0.f;
#pragma unroll
  for (int j = 0; j < 3; j++) {
    const int idx = lane + 64 * j;
    const float4 x0 = xr0[idx];
    const float4 x1 = xr1[idx];
    p00 += dot4(x0, A00[idx]);
    p01 += dot4(x0, A01[idx]);
    p02 += dot4(x0, A02[idx]);
    p10 += dot4(x1, A10[idx]);
    p11 += dot4(x1, A11[idx]);
    p12 += dot4(x1, A12[idx]);
  }
  p00 = wsum(p00); p01 = wsum(p01); p02 = wsum(p02);
  p10 = wsum(p10); p11 = wsum(p11); p12 = wsum(p12);
  if (lane == 0) {
    lgout[3 * n0 + 0] = p00;
    lgout[3 * n0 + 1] = p01;
    lgout[3 * n0 + 2] = p02;
    lgout[3 * n1 + 0] = p10;
    lgout[3 * n1 + 1] = p11;
    lgout[3 * n1 + 2] = p12;
  }
}

// ---- K3: per-bag softmax stats. One wave per bag, no barriers. ----
// Writes wexp[n][3] = exp(lg - bagmax) (unnormalized) and dinv[b][3].
__global__ __launch_bounds__(256) void bagstats(
    const float* __restrict__ lg, const int* __restrict__ scope,
    float* __restrict__ wexp, float* __restrict__ dinv) {
  const int b = blockIdx.x * 4 + (threadIdx.x >> 6);
  const int lane = threadIdx.x & 63;
  const int s0 = scope[b];
  const int s1 = scope[b + 1];
  const int len = s1 - s0;

  float mx0 = -INFINITY, mx1 = -INFINITY, mx2 = -INFINITY;
  for (int i = lane; i < len; i += 64) {
    const int n = s0 + i;
    mx0 = fmaxf(mx0, lg[3 * n + 0]);
    mx1 = fmaxf(mx1, lg[3 * n + 1]);
    mx2 = fmaxf(mx2, lg[3 * n + 2]);
  }
  mx0 = wmax(mx0); mx1 = wmax(mx1); mx2 = wmax(mx2);

  float s0e = 0.f, s1e = 0.f, s2e = 0.f;
  for (int i = lane; i < len; i += 64) {
    const int n = s0 + i;
    const float e0 = __expf(lg[3 * n + 0] - mx0);
    const float e1 = __expf(lg[3 * n + 1] - mx1);
    const float e2 = __expf(lg[3 * n + 2] - mx2);
    wexp[3 * n + 0] = e0;
    wexp[3 * n + 1] = e1;
    wexp[3 * n + 2] = e2;
    s0e += e0; s1e += e1; s2e += e2;
  }
  s0e = wsum(s0e); s1e = wsum(s1e); s2e = wsum(s2e);
  if (lane == 0) {
    dinv[3 * b + 0] = 1.f / s0e;
    dinv[3 * b + 1] = 1.f / s1e;
    dinv[3 * b + 2] = 1.f / s2e;
  }
}

// ---- K4: weighted aggregation. One wave per bag, no barriers, no LDS. ----
// Lane owns 3 float4 columns (lane, lane+64, lane+128); 4-sentence unroll
// keeps 12 x-loads in flight. x is L3-resident (streamed by K2).
__global__ __launch_bounds__(256, 4) void agg(
    const float* __restrict__ x, const float* __restrict__ wexp,
    const float* __restrict__ dinv, const int* __restrict__ scope,
    float* __restrict__ out, unsigned short* __restrict__ lt16) {
  const int b = blockIdx.x * 4 + (threadIdx.x >> 6);
  const int lane = threadIdx.x & 63;
  const int s0 = scope[b];
  const int s1 = scope[b + 1];
  const int len = s1 - s0;

  const float4* __restrict__ X4 = (const float4*)x;

  f32x4 acc[3][3];  // [layer][colgroup]
#pragma unroll
  for (int l = 0; l < 3; l++)
#pragma unroll
    for (int k = 0; k < 3; k++) acc[l][k] = (f32x4){0.f, 0.f, 0.f, 0.f};

  int i = 0;
  for (; i + 4 <= len; i += 4) {
    float w[4][3];
    float4 xv[4][3];
#pragma unroll
    for (int j = 0; j < 4; j++) {
      const int n = s0 + i + j;
      w[j][0] = wexp[3 * n + 0];
      w[j][1] = wexp[3 * n + 1];
      w[j][2] = wexp[3 * n + 2];
#pragma unroll
      for (int k = 0; k < 3; k++)
        xv[j][k] = X4[(size_t)n * D4 + lane + 64 * k];
    }
#pragma unroll
    for (int j = 0; j < 4; j++)
#pragma unroll
      for (int l = 0; l < 3; l++)
#pragma unroll
        for (int k = 0; k < 3; k++) {
          acc[l][k][0] += w[j][l] * xv[j][k].x;
          acc[l][k][1] += w[j][l] * xv[j][k].y;
          acc[l][k][2] += w[j][l] * xv[j][k].z;
          acc[l][k][3] += w[j][l] * xv[j][k].w;
        }
  }
  for (; i < len; i++) {
    const int n = s0 + i;
    const float w0 = wexp[3 * n + 0];
    const float w1 = wexp[3 * n + 1];
    const float w2 = wexp[3 * n + 2];
#pragma unroll
    for (int k = 0; k < 3; k++) {
      const float4 xv = X4[(size_t)n * D4 + lane + 64 * k];
      acc[0][k][0] += w0 * xv.x; acc[0][k][1] += w0 * xv.y;
      acc[0][k][2] += w0 * xv.z; acc[0][k][3] += w0 * xv.w;
      acc[1][k][0] += w1 * xv.x; acc[1][k][1] += w1 * xv.y;
      acc[1][k][2] += w1 * xv.z; acc[1][k][3] += w1 * xv.w;
      acc[2][k][0] += w2 * xv.x; acc[2][k][1] += w2 * xv.y;
      acc[2][k][2] += w2 * xv.z; acc[2][k][3] += w2 * xv.w;
    }
  }

  // epilogue: normalize, write stack [3][B][D], lt [B][3D], lt16 bf16
  float4* o0 = (float4*)out;
  float4* o1 = (float4*)(out + (size_t)3 * NBAGS * DIM);
  ushort4* l16 = (ushort4*)(lt16 + (size_t)b * KTOT);
#pragma unroll
  for (int l = 0; l < 3; l++) {
    const float di = dinv[3 * b + l];
#pragma unroll
    for (int k = 0; k < 3; k++) {
      const int c = lane + 64 * k;  // 0..191
      float4 v;
      v.x = acc[l][k][0] * di;
      v.y = acc[l][k][1] * di;
      v.z = acc[l][k][2] * di;
      v.w = acc[l][k][3] * di;
      o0[((size_t)l * NBAGS + b) * D4 + c] = v;
      o1[(size_t)b * K4 + l * D4 + c] = v;
      ushort4 h;
      h.x = f2bf(v.x); h.y = f2bf(v.y); h.z = f2bf(v.z); h.w = f2bf(v.w);
      l16[l * D4 + c] = h;
    }
  }
}

// ---- K5: probs = lt @ rw^T + bias via bf16 MFMA (64 bags x 64 classes) ----
__global__ __launch_bounds__(256) void probs_mfma(
    const unsigned short* __restrict__ lt16,
    const unsigned short* __restrict__ rw16,
    const float* __restrict__ bias, float* __restrict__ outp) {
  const int wv = threadIdx.x >> 6;
  const int lane = threadIdx.x & 63;
  const int r = lane & 15;
  const int kg = lane >> 4;
  const int bagbase = blockIdx.x * 64 + wv * 16;

  f32x4 acc[4];
#pragma unroll
  for (int ct = 0; ct < 4; ct++) acc[ct] = (f32x4){0.f, 0.f, 0.f, 0.f};

  const unsigned short* ap = lt16 + (size_t)(bagbase + r) * KTOT + kg * 8;
  const unsigned short* bp[4];
#pragma unroll
  for (int ct = 0; ct < 4; ct++)
    bp[ct] = rw16 + (size_t)(ct * 16 + r) * KTOT + kg * 8;

  for (int k = 0; k < KTOT; k += 32) {
    const bf16x8 a = *(const bf16x8*)(ap + k);
#pragma unroll
    for (int ct = 0; ct < 4; ct++) {
      const bf16x8 bb = *(const bf16x8*)(bp[ct] + k);
      acc[ct] = __builtin_amdgcn_mfma_f32_16x16x32_bf16(a, bb, acc[ct], 0, 0, 0);
    }
  }

  // D mapping (m89-verified): col = lane&15, row = (lane>>4)*4 + reg
#pragma unroll
  for (int ct = 0; ct < 4; ct++) {
    const int col = ct * 16 + r;
    if (col < FLATC) {
      const float bv = bias[col];
#pragma unroll
      for (int reg = 0; reg < 4; reg++) {
        const int bag = bagbase + kg * 4 + reg;
        outp[(size_t)bag * FLATC + col] = acc[ct][reg] + bv;
      }
    }
  }
}

extern "C" void kernel_launch(void* const* d_in, const int* in_sizes, int n_in,
                              void* d_out, int out_size, void* d_ws,
                              size_t ws_size, hipStream_t stream) {
  const float* x = (const float*)d_in[0];
  const int* aq = (const int*)d_in[1];
  const int* scope = (const int*)d_in[2];
  const float* aw = (const float*)d_in[3];
  const float* rw = (const float*)d_in[4];
  const float* bias = (const float*)d_in[5];
  float* out = (float*)d_out;

  unsigned short* lt16 = (unsigned short*)d_ws;        // 4096*2304 bf16
  unsigned short* rw16 = lt16 + (size_t)NBAGS * KTOT;  // 64*2304 bf16
  float* lgbuf = (float*)(rw16 + (size_t)CPAD * KTOT); // 65536*3 f32
  float* wexp = lgbuf + (size_t)NSENT * 3;             // 65536*3 f32
  float* dinv = wexp + (size_t)NSENT * 3;              // 4096*3 f32

  hipLaunchKernelGGL(rwcvt, dim3((CPAD * KTOT + 255) / 256), dim3(256), 0,
                     stream, rw, rw16);
  hipLaunchKernelGGL(logit_kernel, dim3(NSENT / 2 / 4), dim3(256), 0, stream,
                     x, aq, aw, lgbuf);
  hipLaunchKernelGGL(bagstats, dim3(NBAGS / 4), dim3(256), 0, stream, lgbuf,
                     scope, wexp, dinv);
  hipLaunchKernelGGL(agg, dim3(NBAGS / 4), dim3(256), 0, stream, x, wexp,
                     dinv, scope, out, lt16);

  float* probs = out + (size_t)3 * NBAGS * DIM + (size_t)NBAGS * KTOT;
  hipLaunchKernelGGL(probs_mfma, dim3(NBAGS / 64), dim3(256), 0, stream, lt16,
                     rw16, bias, probs);
}

// Round 7
// 215.190 us; speedup vs baseline: 1.3732x; 1.3732x over previous
//
#include <hip/hip_runtime.h>
#include <hip/hip_bf16.h>
#include <math.h>

#define NSENT 65536
#define NBAGS 4096
#define DIM 768
#define D4 192            // DIM/4
#define FLATC 53
#define CPAD 64           // padded class count for probs MFMA
#define GCLS 96           // padded global class count (95 real + 1 zero row)
#define KTOT 2304         // 3*DIM
#define K4 576            // KTOT/4
#define CHUNK 512
#define RB 128            // rows per logit_gemm2 block
#define KC 128            // k-chunk (bf16) staged in LDS
#define KSLOT 16          // 16B slots per row (128 bf16 = 256 B)

typedef short bf16x8 __attribute__((ext_vector_type(8)));
typedef float f32x4 __attribute__((ext_vector_type(4)));

__device__ __forceinline__ float wsum(float v) {
#pragma unroll
  for (int o = 32; o; o >>= 1) v += __shfl_xor(v, o);
  return v;
}
__device__ __forceinline__ float wmax(float v) {
#pragma unroll
  for (int o = 32; o; o >>= 1) v = fmaxf(v, __shfl_xor(v, o));
  return v;
}
__device__ __forceinline__ unsigned short f2bf(float f) {
  union { __hip_bfloat16 b; unsigned short s; } cv;
  cv.b = __float2bfloat16(f);
  return cv.s;
}
__device__ __forceinline__ bf16x8 cvt8(float4 lo, float4 hi) {
  union { bf16x8 v; unsigned short s[8]; } u;
  u.s[0] = f2bf(lo.x); u.s[1] = f2bf(lo.y); u.s[2] = f2bf(lo.z); u.s[3] = f2bf(lo.w);
  u.s[4] = f2bf(hi.x); u.s[5] = f2bf(hi.y); u.s[6] = f2bf(hi.z); u.s[7] = f2bf(hi.w);
  return u.v;
}

// ---- K1: aw -> bf16 [96][768] (row 95 zero); rw -> bf16 [64][2304] ----
__global__ __launch_bounds__(256) void cvt_weights(
    const float* __restrict__ aw, const float* __restrict__ rw,
    unsigned short* __restrict__ aw16, unsigned short* __restrict__ rw16) {
  const int idx = blockIdx.x * 256 + threadIdx.x;
  const int NAW = GCLS * DIM;
  if (idx < NAW) {
    const int row = idx / DIM;
    aw16[idx] = f2bf(row < 95 ? aw[idx] : 0.f);
  } else if (idx < NAW + CPAD * KTOT) {
    const int j = idx - NAW;
    const int row = j / KTOT;
    rw16[j] = f2bf(row < FLATC ? rw[j] : 0.f);
  }
}

// ---- K2: L = X @ AW16^T via LDS-staged bf16 MFMA ----
// Block = 128 rows x 96 classes, 4 waves (wave = 32 rows = 2 row-tiles).
// A staged coalesced f32->bf16 into XOR-swizzled LDS; B from L2 (146 KB hot).
__global__ __launch_bounds__(256) void logit_gemm2(
    const float* __restrict__ x, const unsigned short* __restrict__ aw16,
    float* __restrict__ L) {
  __shared__ unsigned short As[RB * KC];  // 32 KB
  const int tid = threadIdx.x;
  const int wv = tid >> 6;
  const int lane = tid & 63;
  const int r = lane & 15;
  const int kg = lane >> 4;
  const int m0 = blockIdx.x * RB;

  f32x4 acc[2][6];
#pragma unroll
  for (int t = 0; t < 2; t++)
#pragma unroll
    for (int ct = 0; ct < 6; ct++) acc[t][ct] = (f32x4){0.f, 0.f, 0.f, 0.f};

  const int arow0 = wv * 32 + r;
  const int arow1 = arow0 + 16;

  for (int kc = 0; kc < DIM; kc += KC) {
    __syncthreads();  // protect As from previous chunk's readers
    // stage: flat f = tid + 256*it; row = f>>4, slot = f&15 (slot = 8 bf16)
#pragma unroll
    for (int it = 0; it < (RB * KSLOT) / 256; ++it) {   // 8 iterations
      const int f = tid + it * 256;
      const int row = f >> 4;
      const int slot = f & 15;
      const float4* src =
          (const float4*)(x + (size_t)(m0 + row) * DIM + kc + slot * 8);
      const bf16x8 v = cvt8(src[0], src[1]);
      *(bf16x8*)(As + (((row << 4) | (slot ^ (row & 7))) << 3)) = v;
    }
    __syncthreads();

    const unsigned short* bp = aw16 + (size_t)r * DIM + kc + kg * 8;
#pragma unroll
    for (int ks = 0; ks < KC; ks += 32) {
      const int sb = (ks >> 3) + kg;  // slot index for this lane's k-slice
      const bf16x8 a0 =
          *(const bf16x8*)(As + (((arow0 << 4) | (sb ^ (arow0 & 7))) << 3));
      const bf16x8 a1 =
          *(const bf16x8*)(As + (((arow1 << 4) | (sb ^ (arow1 & 7))) << 3));
#pragma unroll
      for (int ct = 0; ct < 6; ct++) {
        const bf16x8 b = *(const bf16x8*)(bp + (size_t)ct * 16 * DIM + ks);
        acc[0][ct] = __builtin_amdgcn_mfma_f32_16x16x32_bf16(a0, b, acc[0][ct], 0, 0, 0);
        acc[1][ct] = __builtin_amdgcn_mfma_f32_16x16x32_bf16(a1, b, acc[1][ct], 0, 0, 0);
      }
    }
  }

  // D mapping (m89-verified): col = ct*16 + r, row = tile*16 + kg*4 + reg
#pragma unroll
  for (int t = 0; t < 2; t++)
#pragma unroll
    for (int ct = 0; ct < 6; ct++)
#pragma unroll
      for (int reg = 0; reg < 4; reg++)
        L[(size_t)(m0 + wv * 32 + t * 16 + kg * 4 + reg) * GCLS + ct * 16 + r] =
            acc[t][ct][reg];
}

// ---- K3: lg[n][l] = L[n][q[n][l]] (L is L2/L3-hot) ----
__global__ __launch_bounds__(256) void lgather(
    const float* __restrict__ L, const int* __restrict__ q,
    float* __restrict__ lg) {
  const int n = blockIdx.x * 256 + threadIdx.x;
  if (n >= NSENT) return;
  const int q0 = q[3 * n + 0];
  const int q1 = q[3 * n + 1];
  const int q2 = q[3 * n + 2];
  const float* Lr = L + (size_t)n * GCLS;
  lg[3 * n + 0] = Lr[q0];
  lg[3 * n + 1] = Lr[q1];
  lg[3 * n + 2] = Lr[q2];
}

// ---- K4: per-bag softmax + weighted sum (R4 known-good, ~46 us) ----
__global__ __launch_bounds__(192) void bag_sum(
    const float* __restrict__ x, const float* __restrict__ lgin,
    const int* __restrict__ scope, float* __restrict__ out,
    unsigned short* __restrict__ lt16) {
  const int b = blockIdx.x;
  const int s0 = scope[b];
  const int s1 = scope[b + 1];
  const int len = s1 - s0;
  const int tid = threadIdx.x;
  const int wave = tid >> 6;
  const int lane = tid & 63;

  __shared__ float lg[CHUNK][3];
  __shared__ float sm[3], se[3];

  float m[3] = {-INFINITY, -INFINITY, -INFINITY};
  float dsum[3] = {0.f, 0.f, 0.f};
  float4 acc[3];
#pragma unroll
  for (int l = 0; l < 3; l++) acc[l] = make_float4(0.f, 0.f, 0.f, 0.f);

  const float4* __restrict__ X4 = (const float4*)x;

  for (int cs = 0; cs < len; cs += CHUNK) {
    const int clen = min(CHUNK, len - cs);

    for (int idx = tid; idx < 3 * clen; idx += 192)
      ((float*)lg)[idx] = lgin[(size_t)(s0 + cs) * 3 + idx];
    __syncthreads();

    {
      const int l = wave;
      float cm = -INFINITY;
      for (int i = lane; i < clen; i += 64) cm = fmaxf(cm, lg[i][l]);
      cm = wmax(cm);
      const float mn = fmaxf(m[l], cm);
      float es = 0.f;
      for (int i = lane; i < clen; i += 64) {
        const float e = __expf(lg[i][l] - mn);
        es += e;
        lg[i][l] = e;
      }
      es = wsum(es);
      if (lane == 0) { sm[l] = mn; se[l] = es; }
    }
    __syncthreads();

#pragma unroll
    for (int l = 0; l < 3; l++) {
      const float mn = sm[l];
      const float sc = __expf(m[l] - mn);
      m[l] = mn;
      dsum[l] = dsum[l] * sc + se[l];
      acc[l].x *= sc; acc[l].y *= sc; acc[l].z *= sc; acc[l].w *= sc;
    }

    {
      int i = 0;
      for (; i + 4 <= clen; i += 4) {
        float4 xv[4];
        float w0[4], w1[4], w2[4];
#pragma unroll
        for (int j = 0; j < 4; j++) {
          xv[j] = X4[(size_t)(s0 + cs + i + j) * D4 + tid];
          w0[j] = lg[i + j][0];
          w1[j] = lg[i + j][1];
          w2[j] = lg[i + j][2];
        }
#pragma unroll
        for (int j = 0; j < 4; j++) {
          acc[0].x += w0[j] * xv[j].x; acc[0].y += w0[j] * xv[j].y;
          acc[0].z += w0[j] * xv[j].z; acc[0].w += w0[j] * xv[j].w;
          acc[1].x += w1[j] * xv[j].x; acc[1].y += w1[j] * xv[j].y;
          acc[1].z += w1[j] * xv[j].z; acc[1].w += w1[j] * xv[j].w;
          acc[2].x += w2[j] * xv[j].x; acc[2].y += w2[j] * xv[j].y;
          acc[2].z += w2[j] * xv[j].z; acc[2].w += w2[j] * xv[j].w;
        }
      }
      for (; i < clen; i++) {
        const float a0 = lg[i][0], a1 = lg[i][1], a2 = lg[i][2];
        const float4 xv = X4[(size_t)(s0 + cs + i) * D4 + tid];
        acc[0].x += a0 * xv.x; acc[0].y += a0 * xv.y; acc[0].z += a0 * xv.z; acc[0].w += a0 * xv.w;
        acc[1].x += a1 * xv.x; acc[1].y += a1 * xv.y; acc[1].z += a1 * xv.z; acc[1].w += a1 * xv.w;
        acc[2].x += a2 * xv.x; acc[2].y += a2 * xv.y; acc[2].z += a2 * xv.z; acc[2].w += a2 * xv.w;
      }
    }
    __syncthreads();
  }

  float4* o0 = (float4*)out;                              // stack [3][B][D]
  float4* o1 = (float4*)(out + (size_t)3 * NBAGS * DIM);  // lt [B][3*D]
  ushort4* l16 = (ushort4*)(lt16 + (size_t)b * KTOT);
#pragma unroll
  for (int l = 0; l < 3; l++) {
    const float inv = (dsum[l] > 0.f) ? (1.f / dsum[l]) : 0.f;
    float4 v = acc[l];
    v.x *= inv; v.y *= inv; v.z *= inv; v.w *= inv;
    o0[((size_t)l * NBAGS + b) * D4 + tid] = v;
    o1[(size_t)b * K4 + l * D4 + tid] = v;
    ushort4 h;
    h.x = f2bf(v.x); h.y = f2bf(v.y); h.z = f2bf(v.z); h.w = f2bf(v.w);
    l16[l * D4 + tid] = h;
  }
}

// ---- K5: probs = lt @ rw^T + bias via bf16 MFMA (64 bags x 64 classes) ----
__global__ __launch_bounds__(256) void probs_mfma(
    const unsigned short* __restrict__ lt16,
    const unsigned short* __restrict__ rw16,
    const float* __restrict__ bias, float* __restrict__ outp) {
  const int wv = threadIdx.x >> 6;
  const int lane = threadIdx.x & 63;
  const int r = lane & 15;
  const int kg = lane >> 4;
  const int bagbase = blockIdx.x * 64 + wv * 16;

  f32x4 acc[4];
#pragma unroll
  for (int ct = 0; ct < 4; ct++) acc[ct] = (f32x4){0.f, 0.f, 0.f, 0.f};

  const unsigned short* ap = lt16 + (size_t)(bagbase + r) * KTOT + kg * 8;
  const unsigned short* bp[4];
#pragma unroll
  for (int ct = 0; ct < 4; ct++)
    bp[ct] = rw16 + (size_t)(ct * 16 + r) * KTOT + kg * 8;

  for (int k = 0; k < KTOT; k += 32) {
    const bf16x8 a = *(const bf16x8*)(ap + k);
#pragma unroll
    for (int ct = 0; ct < 4; ct++) {
      const bf16x8 bb = *(const bf16x8*)(bp[ct] + k);
      acc[ct] = __builtin_amdgcn_mfma_f32_16x16x32_bf16(a, bb, acc[ct], 0, 0, 0);
    }
  }

#pragma unroll
  for (int ct = 0; ct < 4; ct++) {
    const int col = ct * 16 + r;
    if (col < FLATC) {
      const float bv = bias[col];
#pragma unroll
      for (int reg = 0; reg < 4; reg++) {
        const int bag = bagbase + kg * 4 + reg;
        outp[(size_t)bag * FLATC + col] = acc[ct][reg] + bv;
      }
    }
  }
}

extern "C" void kernel_launch(void* const* d_in, const int* in_sizes, int n_in,
                              void* d_out, int out_size, void* d_ws,
                              size_t ws_size, hipStream_t stream) {
  const float* x = (const float*)d_in[0];
  const int* aq = (const int*)d_in[1];
  const int* scope = (const int*)d_in[2];
  const float* aw = (const float*)d_in[3];
  const float* rw = (const float*)d_in[4];
  const float* bias = (const float*)d_in[5];
  float* out = (float*)d_out;

  unsigned short* lt16 = (unsigned short*)d_ws;        // 4096*2304 bf16
  unsigned short* rw16 = lt16 + (size_t)NBAGS * KTOT;  // 64*2304 bf16
  unsigned short* aw16 = rw16 + (size_t)CPAD * KTOT;   // 96*768 bf16
  float* L = (float*)(aw16 + (size_t)GCLS * DIM);      // 65536*96 f32
  float* lg = L + (size_t)NSENT * GCLS;                // 65536*3 f32

  const int ncvt = GCLS * DIM + CPAD * KTOT;
  hipLaunchKernelGGL(cvt_weights, dim3((ncvt + 255) / 256), dim3(256), 0,
                     stream, aw, rw, aw16, rw16);
  hipLaunchKernelGGL(logit_gemm2, dim3(NSENT / RB), dim3(256), 0, stream, x,
                     aw16, L);
  hipLaunchKernelGGL(lgather, dim3(NSENT / 256), dim3(256), 0, stream, L, aq,
                     lg);
  hipLaunchKernelGGL(bag_sum, dim3(NBAGS), dim3(192), 0, stream, x, lg, scope,
                     out, lt16);

  float* probs = out + (size_t)3 * NBAGS * DIM + (size_t)NBAGS * KTOT;
  hipLaunchKernelGGL(probs_mfma, dim3(NBAGS / 64), dim3(256), 0, stream, lt16,
                     rw16, bias, probs);
}